// Round 2
// baseline (517.862 us; speedup 1.0000x reference)
//
#include <hip/hip_runtime.h>
#include <stdint.h>

// HopAttentionLayer: B=256, T=64, N=2048, D=128, fp32.
// attention[b,n] = softmax_n( T * dot(context[b,n,:], W[D:2D]) )
//   (tgt_term[b] and T*b0 are constant over n -> cancel in softmax)
// out[b,n,d] = attention[b,n] * context[b,n,d]
//
// R4: 4 blocks per batch (grid 1024, 256 thr) = ~4 independent pipelines/CU.
//  - per-block partial softmax over its 512 rows (LDS), merged across the
//    4 sibling blocks via device-scope atomics in workspace (8B + flag/batch)
//  - desynchronized barrier domains keep read+write streams overlapped;
//    phase-3 re-read stays block-local (256 KiB, L2/L3-hot)
//  - deadlock-safe: <=128 VGPR & 2.1 KiB LDS -> worst-case co-residency
//    capacity >= grid (1024), so the spin-wait always completes.

#define B_DIM 256
#define N_DIM 2048
#define D_DIM 128
#define DVEC  (D_DIM / 4)        // 32 float4 per row
#define T_SCALE 64.0f
#define QPB   4                  // blocks (quarters) per batch
#define ROWS  (N_DIM / QPB)      // 512 rows per block
#define NTHR  256                // 4 waves

typedef float f4v __attribute__((ext_vector_type(4)));

union ms_pack { struct { float m, s; } f; unsigned long long u; };

__global__ __launch_bounds__(NTHR, 4)
void k_hop(const float* __restrict__ ctx, const float* __restrict__ W,
           float* __restrict__ out,
           unsigned long long* __restrict__ ws_ms,   // [B][QPB] packed (m,s)
           unsigned int* __restrict__ ws_flag) {     // [B] arrival counters
    const int tid  = threadIdx.x;
    const int wave = tid >> 6;          // 0..3
    const int lane = tid & 63;
    const int sub  = lane & 31;         // lane within half-wave
    const int half = lane >> 5;
    const int g    = blockIdx.x >> 2;   // batch
    const int q    = blockIdx.x & 3;    // quarter

    __shared__ float sc[ROWS];          // scores -> exp values (2 KiB)
    __shared__ float red[4];
    __shared__ float s_rs;

    const size_t rbase = (size_t)g * N_DIM + (size_t)q * ROWS;
    const f4v* __restrict__ c4 = (const f4v*)ctx + rbase * DVEC;
    f4v*       __restrict__ o4 = (f4v*)out + rbase * DVEC;

    const f4v wc = ((const f4v*)(W + D_DIM))[sub];   // Wc fragment per lane

    // ---- Phase 1: sc[n] = T * dot(ctx[row,:], Wc), 8 rows/iter (4 KiB) ----
    #pragma unroll 4
    for (int it = 0; it < ROWS / 8; ++it) {
        const int n = it * 8 + wave * 2 + half;
        const f4v v = c4[(size_t)n * DVEC + sub];
        float p = v.x * wc.x + v.y * wc.y + v.z * wc.z + v.w * wc.w;
        #pragma unroll
        for (int m = 1; m < 32; m <<= 1) p += __shfl_xor(p, m, 64); // in-half
        if (sub == 0) sc[n] = T_SCALE * p;
    }
    __syncthreads();

    // ---- Phase 2a: block-partial max & sum-of-exp over 512 scores ----
    const float v0 = sc[tid], v1 = sc[tid + NTHR];
    float mx = fmaxf(v0, v1);
    #pragma unroll
    for (int m = 1; m < 64; m <<= 1) mx = fmaxf(mx, __shfl_xor(mx, m, 64));
    if (lane == 0) red[wave] = mx;
    __syncthreads();
    const float mq = fmaxf(fmaxf(red[0], red[1]), fmaxf(red[2], red[3]));
    __syncthreads();                    // red reuse
    const float e0 = __expf(v0 - mq), e1 = __expf(v1 - mq);
    float sm = e0 + e1;
    #pragma unroll
    for (int m = 1; m < 64; m <<= 1) sm += __shfl_xor(sm, m, 64);
    if (lane == 0) red[wave] = sm;
    sc[tid] = e0; sc[tid + NTHR] = e1;  // own elements only: no hazard
    __syncthreads();
    const float sq = red[0] + red[1] + red[2] + red[3];

    // ---- Phase 2b: merge the 4 sibling partials via device-scope atomics ----
    if (tid == 0) {
        ms_pack pk; pk.f.m = mq; pk.f.s = sq;
        __hip_atomic_store(&ws_ms[g * QPB + q], pk.u,
                           __ATOMIC_RELAXED, __HIP_MEMORY_SCOPE_AGENT);
        __hip_atomic_fetch_add(&ws_flag[g], 1u,
                               __ATOMIC_RELEASE, __HIP_MEMORY_SCOPE_AGENT);
        while (__hip_atomic_load(&ws_flag[g], __ATOMIC_ACQUIRE,
                                 __HIP_MEMORY_SCOPE_AGENT) < QPB)
            __builtin_amdgcn_s_sleep(1);
        ms_pack pp[QPB];
        float M = -3.4e38f;
        #pragma unroll
        for (int i = 0; i < QPB; ++i) {
            pp[i].u = __hip_atomic_load(&ws_ms[g * QPB + i],
                                        __ATOMIC_RELAXED,
                                        __HIP_MEMORY_SCOPE_AGENT);
            M = fmaxf(M, pp[i].f.m);
        }
        float S = 0.f;
        #pragma unroll
        for (int i = 0; i < QPB; ++i) S += pp[i].f.s * __expf(pp[i].f.m - M);
        s_rs = __expf(mq - M) / S;      // rescale for THIS block's e-values
    }
    __syncthreads();
    const float rs = s_rs;
    sc[tid] *= rs; sc[tid + NTHR] *= rs;
    __syncthreads();

    // ---- Phase 3: out[row,:] = sc[row] * ctx[row,:] (re-read is cache-hot) --
    #pragma unroll 4
    for (int i = 0; i < (ROWS * DVEC) / NTHR; ++i) {  // 64 iters
        const int f = i * NTHR + tid;
        const float w = sc[f >> 5];
        f4v v = __builtin_nontemporal_load(&c4[f]);
        v *= w;
        __builtin_nontemporal_store(v, &o4[f]);
    }
}

extern "C" void kernel_launch(void* const* d_in, const int* in_sizes, int n_in,
                              void* d_out, int out_size, void* d_ws, size_t ws_size,
                              hipStream_t stream) {
    (void)in_sizes; (void)n_in; (void)out_size; (void)ws_size;
    // d_in[0] = targetsentence_emb (unused: cancels in softmax)
    // d_in[1] = context_emb, d_in[2] = W, d_in[3] = b (unused: cancels)
    const float* ctx = (const float*)d_in[1];
    const float* W   = (const float*)d_in[2];
    float* out       = (float*)d_out;

    unsigned long long* ws_ms = (unsigned long long*)d_ws;          // 8 KiB
    unsigned int* ws_flag     = (unsigned int*)((char*)d_ws + 8192); // 1 KiB

    hipMemsetAsync(ws_flag, 0, B_DIM * sizeof(unsigned int), stream);
    hipLaunchKernelGGL(k_hop, dim3(B_DIM * QPB), dim3(NTHR), 0, stream,
                       ctx, W, out, ws_ms, ws_flag);
}

// Round 3
// 479.359 us; speedup vs baseline: 1.0803x; 1.0803x over previous
//
#include <hip/hip_runtime.h>

// HopAttentionLayer: B=256, T=64, N=2048, D=128, fp32.
// attention[b,n] = softmax_n( T * dot(context[b,n,:], W[D:2D]) )
//   (tgt_term[b] and T*b0 are constant over n -> cancel in softmax)
// out[b,n,d] = attention[b,n] * context[b,n,d]
//
// R5: fused single-block-per-batch (R3 structure, no cross-block atomics —
// R4 showed those regress), with phase 1 rebuilt for deep MLP:
//  - 16 independent float4 loads in flight per thread per iteration
//    (R3 had ~4: latency-bound at 2 TB/s by Little's law; 16 waves x 16
//    loads x 16B = 4 KB in flight/CU vs ~1 KB before)
//  - shuffle-reduce chains for the 16 slots are independent -> interleaved
//  - __launch_bounds__(1024,4) caps VGPR at 128 so 16 waves/CU is kept
//  - phase 3 unroll-8; nt stores keep the 256 MiB output stream from
//    evicting the cached ctx lines it re-reads.

#define B_DIM 256
#define N_DIM 2048
#define D_DIM 128
#define DVEC  (D_DIM / 4)      // 32 float4 per row
#define NTHR  1024             // 16 waves
#define T_SCALE 64.0f
#define G     16               // row-slots per wave per phase-1 iteration

typedef float f4v __attribute__((ext_vector_type(4)));

__global__ __launch_bounds__(NTHR, 4)
void k_fused(const float* __restrict__ ctx, const float* __restrict__ W,
             float* __restrict__ out) {
    const int tid  = threadIdx.x;
    const int wave = tid >> 6;          // 0..15
    const int lane = tid & 63;
    const int sub  = lane & 31;         // lane within half-wave
    const int half = lane >> 5;
    const int b    = blockIdx.x;

    __shared__ float sm[N_DIM];         // scores -> probabilities (8 KiB)
    __shared__ float red[16];

    const size_t cbase = (size_t)b * ((size_t)N_DIM * DVEC);
    const f4v* __restrict__ c4 = (const f4v*)ctx + cbase;
    f4v*       __restrict__ o4 = (f4v*)out + cbase;

    const f4v wc = ((const f4v*)(W + D_DIM))[sub];   // Wc fragment per lane

    // ---- Phase 1: sm[n] = T * dot(ctx[b,n,:], Wc) ----
    // Each wave: 32 rows (16 KiB contiguous) per iteration as 16 row-pair
    // slots; all 16 loads issue before any reduce -> 16 outstanding/thread.
    for (int it = 0; it < N_DIM / (G * 32); ++it) {      // 4 iterations
        const int nb = it * (G * 32) + wave * (2 * G);
        f4v  v[G];
        float p[G];
        #pragma unroll
        for (int s = 0; s < G; ++s)
            v[s] = c4[(size_t)(nb + 2 * s + half) * DVEC + sub];
        #pragma unroll
        for (int s = 0; s < G; ++s)
            p[s] = v[s].x * wc.x + v[s].y * wc.y + v[s].z * wc.z + v[s].w * wc.w;
        #pragma unroll
        for (int m = 1; m < 32; m <<= 1) {               // in-half reduce
            #pragma unroll
            for (int s = 0; s < G; ++s)
                p[s] += __shfl_xor(p[s], m, 64);
        }
        if (sub == 0) {
            #pragma unroll
            for (int s = 0; s < G; ++s)
                sm[nb + 2 * s + half] = T_SCALE * p[s];
        }
    }
    __syncthreads();

    // ---- Phase 2: softmax over sm[0..2047], entirely on-chip ----
    const float a0 = sm[tid];
    const float a1 = sm[tid + NTHR];
    float mx = fmaxf(a0, a1);
    #pragma unroll
    for (int m = 1; m < 64; m <<= 1) mx = fmaxf(mx, __shfl_xor(mx, m, 64));
    if (lane == 0) red[wave] = mx;
    __syncthreads();
    float gmax = red[0];
    #pragma unroll
    for (int i = 1; i < 16; ++i) gmax = fmaxf(gmax, red[i]);

    const float e0 = __expf(a0 - gmax);
    const float e1 = __expf(a1 - gmax);
    float s = e0 + e1;
    #pragma unroll
    for (int m = 1; m < 64; m <<= 1) s += __shfl_xor(s, m, 64);
    __syncthreads();                    // all done reading red (max)
    if (lane == 0) red[wave] = s;
    __syncthreads();
    float tot = red[0];
    #pragma unroll
    for (int i = 1; i < 16; ++i) tot += red[i];
    const float inv = 1.0f / tot;

    sm[tid]        = e0 * inv;
    sm[tid + NTHR] = e1 * inv;
    __syncthreads();

    // ---- Phase 3: out[n,:] = sm[n] * ctx[n,:] (re-read is cache-hot) ----
    #pragma unroll 8
    for (int i = 0; i < (N_DIM * DVEC) / NTHR; ++i) {   // 64 iters
        const int f = i * NTHR + tid;
        const float w = sm[f >> 5];
        f4v v = c4[f];
        v *= w;
        __builtin_nontemporal_store(v, &o4[f]);
    }
}

extern "C" void kernel_launch(void* const* d_in, const int* in_sizes, int n_in,
                              void* d_out, int out_size, void* d_ws, size_t ws_size,
                              hipStream_t stream) {
    (void)in_sizes; (void)n_in; (void)out_size; (void)d_ws; (void)ws_size;
    // d_in[0] = targetsentence_emb (unused: cancels in softmax)
    // d_in[1] = context_emb, d_in[2] = W, d_in[3] = b (unused: cancels)
    const float* ctx = (const float*)d_in[1];
    const float* W   = (const float*)d_in[2];
    float* out       = (float*)d_out;

    hipLaunchKernelGGL(k_fused, dim3(B_DIM), dim3(NTHR), 0, stream,
                       ctx, W, out);
}